// Round 4
// baseline (1991.632 us; speedup 1.0000x reference)
//
#include <hip/hip_runtime.h>
#include <math.h>

#define NBLK  11
#define NAGG  4
#define NFILT 32
#define NPROP 20
#define BB    128
#define VV    1024
#define HV    512
#define FIN   10
#define TPB   512
#define BN_EPS 1e-3f

// d_ws layout: [0..127] int flags (memset 0 per launch);
// floats: mean partials at [128 .. 128+128*2*10), agg partials after.
#define WSF_MEAN 128
#define WSF_AGG  (WSF_MEAN + BB*2*FIN)

__device__ __forceinline__ float fast_tanh(float x){
  float a = fabsf(x);
  float e = __expf(-2.0f * a);
  float r = (1.0f - e) / (1.0f + e);
  return copysignf(r, x);
}

// pairwise event sync: each WG posts once, waits until both posted.
__device__ __forceinline__ void pair_sync(int* flag, int target){
  __syncthreads();
  if (threadIdx.x == 0){
    __threadfence();
    __hip_atomic_fetch_add(flag, 1, __ATOMIC_RELEASE, __HIP_MEMORY_SCOPE_AGENT);
    while (__hip_atomic_load(flag, __ATOMIC_ACQUIRE, __HIP_MEMORY_SCOPE_AGENT) < target)
      __builtin_amdgcn_s_sleep(2);
  }
  __syncthreads();
}

// waves_per_eu(2): target exactly 2 waves/SIMD (the 512-thr/1-WG-per-CU case)
// -> 256-VGPR budget, so the ~150-reg live set never touches scratch.
extern "C" __global__ __launch_bounds__(TPB)
__attribute__((amdgpu_waves_per_eu(2)))
void garnet_fused(
    const float* __restrict__ x,
    const float* __restrict__ bn0_g, const float* __restrict__ bn0_b,
    const float* __restrict__ bn0_m, const float* __restrict__ bn0_v,
    const float* __restrict__ W_in,  const float* __restrict__ b_in,
    const float* __restrict__ W_flr, const float* __restrict__ b_flr,
    const float* __restrict__ W_s,   const float* __restrict__ b_s,
    const float* __restrict__ W_out, const float* __restrict__ b_out,
    const float* __restrict__ bn_g,  const float* __restrict__ bn_b,
    const float* __restrict__ bn_m,  const float* __restrict__ bn_v,
    const float* __restrict__ W_o0,  const float* __restrict__ b_o0,
    const float* __restrict__ W_o1,  const float* __restrict__ b_o1,
    int* __restrict__ wsFlag, float* __restrict__ wsF,
    float* __restrict__ out)
{
  const int wg   = blockIdx.x;
  const int b    = wg & (BB - 1);     // partner wg = wg^128 -> same XCD (wg%8 equal)
  const int half = wg >> 7;
  const int t    = threadIdx.x;
  const int lane = t & 63;
  const int wave = t >> 6;
  const int v    = half * HV + t;     // global vertex this thread owns
  const int sw   = t & 7;             // LDS granule swizzle for own row

  __shared__ float sFeat[HV][32];     // 64 KB, rows 128B, XOR-swizzled granules
  __shared__ float sAgg[NAGG][48];
  __shared__ float sM[NAGG][NFILT];
  __shared__ float sRed[8][FIN];
  __shared__ float sMean[FIN];

  int* flag = wsFlag + b;

  // ---------------- phase 0: mean over V (cross-half) + input dense ----------------
  float h[NFILT];
  {
    float xv[FIN];
    const float* xp = x + ((size_t)b * VV + v) * FIN;
    #pragma unroll
    for (int c = 0; c < FIN; ++c) xv[c] = xp[c];

    float ps[FIN];
    #pragma unroll
    for (int c = 0; c < FIN; ++c) ps[c] = xv[c];
    #pragma unroll
    for (int m = 32; m > 0; m >>= 1){
      #pragma unroll
      for (int c = 0; c < FIN; ++c) ps[c] += __shfl_xor(ps[c], m, 64);
    }
    if (lane == 0){
      #pragma unroll
      for (int c = 0; c < FIN; ++c) sRed[wave][c] = ps[c];
    }
    __syncthreads();
    if (t < FIN){
      float s = 0.f;
      #pragma unroll
      for (int wv = 0; wv < 8; ++wv) s += sRed[wv][t];
      sRed[0][t] = s;                                   // my half-partial
      __hip_atomic_store(&wsF[WSF_MEAN + (b*2 + half)*FIN + t], s,
                         __ATOMIC_RELAXED, __HIP_MEMORY_SCOPE_AGENT);
      __threadfence();
    }
    pair_sync(flag, 2);
    if (t < FIN){
      float theirs = __hip_atomic_load(&wsF[WSF_MEAN + (b*2 + (half^1))*FIN + t],
                                       __ATOMIC_RELAXED, __HIP_MEMORY_SCOPE_AGENT);
      sMean[t] = (sRed[0][t] + theirs) * (1.0f / VV);
    }
    __syncthreads();

    // h = tanh(bn0(concat(x,mean)) @ W_in + b_in)
    float o[NFILT];
    #pragma unroll
    for (int j = 0; j < NFILT; ++j) o[j] = b_in[j];
    #pragma unroll
    for (int c = 0; c < FIN; ++c){
      const float zx = (xv[c]    - bn0_m[c])     * (bn0_g[c]     * rsqrtf(bn0_v[c]     + BN_EPS)) + bn0_b[c];
      const float zm = (sMean[c] - bn0_m[FIN+c]) * (bn0_g[FIN+c] * rsqrtf(bn0_v[FIN+c] + BN_EPS)) + bn0_b[FIN+c];
      #pragma unroll
      for (int j = 0; j < NFILT; ++j)
        o[j] += zx * W_in[c*NFILT + j] + zm * W_in[(FIN+c)*NFILT + j];
    }
    #pragma unroll
    for (int j = 0; j < NFILT; ++j) h[j] = fast_tanh(o[j]);
  }

  // fused head accumulator: acc48 = b_o0 + sum_l out_l @ W_o0[l*32:(l+1)*32,:]
  float acc[48];
  #pragma unroll
  for (int n = 0; n < 48; ++n) acc[n] = b_o0[n];

  float w[NAGG];

  for (int l = 0; l < NBLK; ++l){
    const float* Wf = W_flr + l * NFILT * NPROP;
    const float* bf = b_flr + l * NPROP;
    const float* Ws = W_s   + l * NFILT * NAGG;
    const float* bs = b_s   + l * NAGG;
    const float* Wo = W_out + l * 228 * NFILT;
    const float* bo = b_out + l * NFILT;
    const float* g_ = bn_g  + l * NFILT;
    const float* be = bn_b  + l * NFILT;
    const float* bm = bn_m  + l * NFILT;
    const float* bv = bn_v  + l * NFILT;

    // ---- stage 1: f = h@Wf+bf, d = h@Ws+bs, w = exp(-|d|); feat -> LDS ----
    {
      float f[NPROP];
      #pragma unroll
      for (int p = 0; p < NPROP; ++p) f[p] = bf[p];
      float d[NAGG];
      #pragma unroll
      for (int a = 0; a < NAGG; ++a) d[a] = bs[a];
      #pragma unroll
      for (int k = 0; k < NFILT; ++k){
        const float hk = h[k];
        #pragma unroll
        for (int p = 0; p < NPROP; ++p) f[p] += hk * Wf[k*NPROP + p];
        #pragma unroll
        for (int a = 0; a < NAGG; ++a)  d[a] += hk * Ws[k*NAGG + a];
      }
      #pragma unroll
      for (int a = 0; a < NAGG; ++a) w[a] = __expf(-fabsf(d[a]));
      #pragma unroll
      for (int q = 0; q < 5; ++q)
        *(float4*)&sFeat[t][((q ^ sw) << 2)] = make_float4(f[4*q], f[4*q+1], f[4*q+2], f[4*q+3]);
      *(float4*)&sFeat[t][((5 ^ sw) << 2)] = make_float4(w[0], w[1], w[2], w[3]);
    }
    __syncthreads();

    // ---- stage 2: partial max/sum over this half's 512 rows; wave g owns c-quad g ----
    if (wave < 6){
      const int g = wave;
      float psum[NAGG][4], pmax[NAGG][4];
      #pragma unroll
      for (int a = 0; a < NAGG; ++a)
        #pragma unroll
        for (int c = 0; c < 4; ++c){ psum[a][c] = 0.f; pmax[a][c] = -INFINITY; }
      #pragma unroll 2
      for (int i = 0; i < 8; ++i){
        const int row = i * 64 + lane;
        const int rs  = row & 7;
        const float4 fq = *(const float4*)&sFeat[row][((g ^ rs) << 2)];
        const float4 wq = *(const float4*)&sFeat[row][((5 ^ rs) << 2)];
        const float fc[4] = {fq.x, fq.y, fq.z, fq.w};
        const float wa[4] = {wq.x, wq.y, wq.z, wq.w};
        #pragma unroll
        for (int a = 0; a < NAGG; ++a)
          #pragma unroll
          for (int c = 0; c < 4; ++c){
            const float p = wa[a] * fc[c];
            psum[a][c] += p;
            pmax[a][c]  = fmaxf(pmax[a][c], p);
          }
      }
      #pragma unroll
      for (int m = 32; m > 0; m >>= 1){
        #pragma unroll
        for (int a = 0; a < NAGG; ++a)
          #pragma unroll
          for (int c = 0; c < 4; ++c){
            psum[a][c] += __shfl_xor(psum[a][c], m, 64);
            pmax[a][c]  = fmaxf(pmax[a][c], __shfl_xor(pmax[a][c], m, 64));
          }
      }
      if (lane == 0){
        float* gp = wsF + WSF_AGG + (((size_t)(b*2 + (l&1))*2 + half) * NAGG * 48);
        #pragma unroll
        for (int a = 0; a < NAGG; ++a)
          #pragma unroll
          for (int c = 0; c < 4; ++c){
            sAgg[a][g*4 + c]      = pmax[a][c];          // raw partial max
            sAgg[a][24 + g*4 + c] = psum[a][c];          // raw partial sum
            __hip_atomic_store(&gp[a*48 + g*4 + c],      pmax[a][c], __ATOMIC_RELAXED, __HIP_MEMORY_SCOPE_AGENT);
            __hip_atomic_store(&gp[a*48 + 24 + g*4 + c], psum[a][c], __ATOMIC_RELAXED, __HIP_MEMORY_SCOPE_AGENT);
          }
        __threadfence();
      }
    }
    pair_sync(flag, 2*l + 4);

    // ---- combine halves: max of maxes, mean = (sum0+sum1)/V ----
    if (t < 192){
      const int a = t / 48, c = t - a * 48;
      const float* pp = wsF + WSF_AGG + (((size_t)(b*2 + (l&1))*2 + (half^1)) * NAGG * 48);
      const float mine   = sAgg[a][c];
      const float theirs = __hip_atomic_load(&pp[a*48 + c], __ATOMIC_RELAXED, __HIP_MEMORY_SCOPE_AGENT);
      sAgg[a][c] = (c < 24) ? fmaxf(mine, theirs) : (mine + theirs) * (1.0f / VV);
    }
    __syncthreads();

    // ---- M'[a][j] = sum_c agg[a][c]*Wo[32+a*48+c][j] + Wo[224+a][j] ----
    if (t < 128){
      const int a = t >> 5, j = t & 31;
      float m = Wo[(224 + a) * NFILT + j];
      #pragma unroll 8
      for (int c = 0; c < 48; ++c) m += sAgg[a][c] * Wo[(32 + a*48 + c) * NFILT + j];
      sM[a][j] = m;
    }
    __syncthreads();

    // ---- stage 3: out_j = bn(tanh(h@WoH + w@M' + bo)); acc += out@Wo0_slice ----
    // new h buffered in regs (hn) -- h must stay old for the whole q-loop.
    float hn[NFILT];
    #pragma unroll
    for (int q = 0; q < 8; ++q){
      const float4 m0 = *(const float4*)&sM[0][q*4];
      const float4 m1 = *(const float4*)&sM[1][q*4];
      const float4 m2 = *(const float4*)&sM[2][q*4];
      const float4 m3 = *(const float4*)&sM[3][q*4];
      float val[4];
      #pragma unroll
      for (int jj = 0; jj < 4; ++jj){
        const int j = q*4 + jj;
        const float mqa = (jj==0) ? m0.x : (jj==1) ? m0.y : (jj==2) ? m0.z : m0.w;
        const float mqb = (jj==0) ? m1.x : (jj==1) ? m1.y : (jj==2) ? m1.z : m1.w;
        const float mqc = (jj==0) ? m2.x : (jj==1) ? m2.y : (jj==2) ? m2.z : m2.w;
        const float mqd = (jj==0) ? m3.x : (jj==1) ? m3.y : (jj==2) ? m3.z : m3.w;
        float o = bo[j] + w[0]*mqa + w[1]*mqb + w[2]*mqc + w[3]*mqd;
        #pragma unroll
        for (int k = 0; k < NFILT; ++k) o += h[k] * Wo[k*NFILT + j];
        const float th = fast_tanh(o);
        val[jj] = (th - bm[j]) * (g_[j] * rsqrtf(bv[j] + BN_EPS)) + be[j];
      }
      #pragma unroll
      for (int jj = 0; jj < 4; ++jj){
        const int j = q*4 + jj;
        const float* wrow = W_o0 + ((size_t)(l*NFILT + j)) * 48;
        #pragma unroll
        for (int n = 0; n < 48; ++n) acc[n] += val[jj] * wrow[n];
        hn[j] = val[jj];
      }
    }
    #pragma unroll
    for (int j = 0; j < NFILT; ++j) h[j] = hn[j];
  }

  // ---------------- head: relu(acc48) @ W_o1 + b_o1, relu ----------------
  {
    float o3[3] = {b_o1[0], b_o1[1], b_o1[2]};
    #pragma unroll
    for (int n = 0; n < 48; ++n){
      const float hn2 = fmaxf(acc[n], 0.f);
      o3[0] += hn2 * W_o1[n*3 + 0];
      o3[1] += hn2 * W_o1[n*3 + 1];
      o3[2] += hn2 * W_o1[n*3 + 2];
    }
    float* op = out + ((size_t)b * VV + v) * 3;
    op[0] = fmaxf(o3[0], 0.f);
    op[1] = fmaxf(o3[1], 0.f);
    op[2] = fmaxf(o3[2], 0.f);
  }
}

extern "C" void kernel_launch(void* const* d_in, const int* in_sizes, int n_in,
                              void* d_out, int out_size, void* d_ws, size_t ws_size,
                              hipStream_t stream) {
  const float* x      = (const float*)d_in[0];
  const float* bn0_g  = (const float*)d_in[1];
  const float* bn0_b  = (const float*)d_in[2];
  const float* bn0_m  = (const float*)d_in[3];
  const float* bn0_v  = (const float*)d_in[4];
  const float* W_in   = (const float*)d_in[5];
  const float* b_in   = (const float*)d_in[6];
  const float* W_flr  = (const float*)d_in[7];
  const float* b_flr  = (const float*)d_in[8];
  const float* W_s    = (const float*)d_in[9];
  const float* b_s    = (const float*)d_in[10];
  const float* W_out  = (const float*)d_in[11];
  const float* b_out  = (const float*)d_in[12];
  const float* bn_g   = (const float*)d_in[13];
  const float* bn_b   = (const float*)d_in[14];
  const float* bn_m   = (const float*)d_in[15];
  const float* bn_v   = (const float*)d_in[16];
  const float* W_o0   = (const float*)d_in[17];
  const float* b_o0   = (const float*)d_in[18];
  const float* W_o1   = (const float*)d_in[19];
  const float* b_o1   = (const float*)d_in[20];

  // reset pairwise sync flags (graph-capture-safe)
  hipMemsetAsync(d_ws, 0, BB * sizeof(int), stream);

  // 24 KB dynamic LDS pads static ~67 KB past 80 KB -> exactly 1 WG/CU,
  // so the 256 WGs spread across all 256 CUs.
  garnet_fused<<<dim3(BB * 2), dim3(TPB), 24 * 1024, stream>>>(
      x, bn0_g, bn0_b, bn0_m, bn0_v, W_in, b_in,
      W_flr, b_flr, W_s, b_s, W_out, b_out,
      bn_g, bn_b, bn_m, bn_v, W_o0, b_o0, W_o1, b_o1,
      (int*)d_ws, (float*)d_ws, (float*)d_out);
}

// Round 5
// 1580.921 us; speedup vs baseline: 1.2598x; 1.2598x over previous
//
#include <hip/hip_runtime.h>
#include <math.h>

#define NBLK  11
#define NAGG  4
#define NFILT 32
#define NPROP 20
#define BB    128
#define VV    1024
#define HV    512
#define FIN   10
#define TPB   512
#define BN_EPS 1e-3f

// d_ws layout: [0..127] int flags (memset 0 per launch);
// floats: mean partials at [128 .. 128+128*2*10), agg partials after.
#define WSF_MEAN 128
#define WSF_AGG  (WSF_MEAN + BB*2*FIN)

__device__ __forceinline__ float fast_tanh(float x){
  float a = fabsf(x);
  float e = __expf(-2.0f * a);
  float r = (1.0f - e) / (1.0f + e);
  return copysignf(r, x);
}

// pairwise event sync: each WG posts once (RELEASE), spins (ACQUIRE) until both posted.
// release-add / acquire-load at agent scope orders the preceding relaxed data
// stores against the partner's post-spin data loads (cross-XCD safe).
__device__ __forceinline__ void pair_sync(int* flag, int target){
  __syncthreads();
  if (threadIdx.x == 0){
    __hip_atomic_fetch_add(flag, 1, __ATOMIC_RELEASE, __HIP_MEMORY_SCOPE_AGENT);
    while (__hip_atomic_load(flag, __ATOMIC_ACQUIRE, __HIP_MEMORY_SCOPE_AGENT) < target)
      __builtin_amdgcn_s_sleep(2);
  }
  __syncthreads();
}

extern "C" __global__ __launch_bounds__(TPB)
void garnet_fused(
    const float* __restrict__ x,
    const float* __restrict__ bn0_g, const float* __restrict__ bn0_b,
    const float* __restrict__ bn0_m, const float* __restrict__ bn0_v,
    const float* __restrict__ W_in,  const float* __restrict__ b_in,
    const float* __restrict__ W_flr, const float* __restrict__ b_flr,
    const float* __restrict__ W_s,   const float* __restrict__ b_s,
    const float* __restrict__ W_out, const float* __restrict__ b_out,
    const float* __restrict__ bn_g,  const float* __restrict__ bn_b,
    const float* __restrict__ bn_m,  const float* __restrict__ bn_v,
    const float* __restrict__ W_o0,  const float* __restrict__ b_o0,
    const float* __restrict__ W_o1,  const float* __restrict__ b_o1,
    int* __restrict__ wsFlag, float* __restrict__ wsF,
    float* __restrict__ out)
{
  const int wg   = blockIdx.x;
  const int b    = wg & (BB - 1);     // partner wg = wg^128 -> same XCD (wg%8 equal)
  const int half = wg >> 7;
  const int t    = threadIdx.x;
  const int lane = t & 63;
  const int wave = t >> 6;
  const int v    = half * HV + t;     // global vertex this thread owns
  const int sw   = t & 7;             // LDS granule swizzle for own row

  __shared__ float sFeat[HV][32];     // 64 KB, rows 128B, XOR-swizzled granules
  __shared__ float sAgg[NAGG][48];
  __shared__ float sM[NAGG][NFILT];
  __shared__ float sRed[8][FIN];
  __shared__ float sMean[FIN];
  // sPad pushes STATIC LDS past 80 KB so the compiler's occupancy model derives
  // 1 WG/CU -> 2 waves/EU -> 256-VGPR budget (it was capping at 128 with 67.5 KB
  // static, assuming 2 WGs/CU). Guarded by a runtime-opaque never-taken branch
  // so it cannot be elided.
  __shared__ float sPad[4096];        // 16 KB
  if (__builtin_expect(wsFlag == nullptr, 0)){
    sPad[t] = (float)t;
    __syncthreads();
    out[t] = sPad[(TPB - 1) - t];
  }

  int* flag = wsFlag + b;

  // ---------------- phase 0: mean over V (cross-half) + input dense ----------------
  float h[NFILT];
  {
    float xv[FIN];
    const float* xp = x + ((size_t)b * VV + v) * FIN;
    #pragma unroll
    for (int c = 0; c < FIN; ++c) xv[c] = xp[c];

    float ps[FIN];
    #pragma unroll
    for (int c = 0; c < FIN; ++c) ps[c] = xv[c];
    #pragma unroll
    for (int m = 32; m > 0; m >>= 1){
      #pragma unroll
      for (int c = 0; c < FIN; ++c) ps[c] += __shfl_xor(ps[c], m, 64);
    }
    if (lane == 0){
      #pragma unroll
      for (int c = 0; c < FIN; ++c) sRed[wave][c] = ps[c];
    }
    __syncthreads();
    if (t < FIN){
      float s = 0.f;
      #pragma unroll
      for (int wv = 0; wv < 8; ++wv) s += sRed[wv][t];
      sRed[0][t] = s;                                   // my half-partial
      __hip_atomic_store(&wsF[WSF_MEAN + (b*2 + half)*FIN + t], s,
                         __ATOMIC_RELAXED, __HIP_MEMORY_SCOPE_AGENT);
    }
    pair_sync(flag, 2);
    if (t < FIN){
      float theirs = __hip_atomic_load(&wsF[WSF_MEAN + (b*2 + (half^1))*FIN + t],
                                       __ATOMIC_RELAXED, __HIP_MEMORY_SCOPE_AGENT);
      sMean[t] = (sRed[0][t] + theirs) * (1.0f / VV);
    }
    __syncthreads();

    // h = tanh(bn0(concat(x,mean)) @ W_in + b_in)
    float o[NFILT];
    #pragma unroll
    for (int j = 0; j < NFILT; ++j) o[j] = b_in[j];
    #pragma unroll
    for (int c = 0; c < FIN; ++c){
      const float zx = (xv[c]    - bn0_m[c])     * (bn0_g[c]     * rsqrtf(bn0_v[c]     + BN_EPS)) + bn0_b[c];
      const float zm = (sMean[c] - bn0_m[FIN+c]) * (bn0_g[FIN+c] * rsqrtf(bn0_v[FIN+c] + BN_EPS)) + bn0_b[FIN+c];
      #pragma unroll
      for (int j = 0; j < NFILT; ++j)
        o[j] += zx * W_in[c*NFILT + j] + zm * W_in[(FIN+c)*NFILT + j];
    }
    #pragma unroll
    for (int j = 0; j < NFILT; ++j) h[j] = fast_tanh(o[j]);
  }

  // fused head accumulator: acc48 = b_o0 + sum_l out_l @ W_o0[l*32:(l+1)*32,:]
  float acc[48];
  #pragma unroll
  for (int n = 0; n < 48; ++n) acc[n] = b_o0[n];

  float w[NAGG];

  for (int l = 0; l < NBLK; ++l){
    const float* Wf = W_flr + l * NFILT * NPROP;
    const float* bf = b_flr + l * NPROP;
    const float* Ws = W_s   + l * NFILT * NAGG;
    const float* bs = b_s   + l * NAGG;
    const float* Wo = W_out + l * 228 * NFILT;
    const float* bo = b_out + l * NFILT;
    const float* g_ = bn_g  + l * NFILT;
    const float* be = bn_b  + l * NFILT;
    const float* bm = bn_m  + l * NFILT;
    const float* bv = bn_v  + l * NFILT;

    // ---- stage 1: f = h@Wf+bf, d = h@Ws+bs, w = exp(-|d|); feat -> LDS ----
    {
      float f[NPROP];
      #pragma unroll
      for (int p = 0; p < NPROP; ++p) f[p] = bf[p];
      float d[NAGG];
      #pragma unroll
      for (int a = 0; a < NAGG; ++a) d[a] = bs[a];
      #pragma unroll
      for (int k = 0; k < NFILT; ++k){
        const float hk = h[k];
        #pragma unroll
        for (int p = 0; p < NPROP; ++p) f[p] += hk * Wf[k*NPROP + p];
        #pragma unroll
        for (int a = 0; a < NAGG; ++a)  d[a] += hk * Ws[k*NAGG + a];
      }
      #pragma unroll
      for (int a = 0; a < NAGG; ++a) w[a] = __expf(-fabsf(d[a]));
      #pragma unroll
      for (int q = 0; q < 5; ++q)
        *(float4*)&sFeat[t][((q ^ sw) << 2)] = make_float4(f[4*q], f[4*q+1], f[4*q+2], f[4*q+3]);
      *(float4*)&sFeat[t][((5 ^ sw) << 2)] = make_float4(w[0], w[1], w[2], w[3]);
    }
    __syncthreads();

    // ---- stage 2: partial max/sum over this half's 512 rows; wave g owns c-quad g ----
    if (wave < 6){
      const int g = wave;
      float psum[NAGG][4], pmax[NAGG][4];
      #pragma unroll
      for (int a = 0; a < NAGG; ++a)
        #pragma unroll
        for (int c = 0; c < 4; ++c){ psum[a][c] = 0.f; pmax[a][c] = -INFINITY; }
      #pragma unroll 2
      for (int i = 0; i < 8; ++i){
        const int row = i * 64 + lane;
        const int rs  = row & 7;
        const float4 fq = *(const float4*)&sFeat[row][((g ^ rs) << 2)];
        const float4 wq = *(const float4*)&sFeat[row][((5 ^ rs) << 2)];
        const float fc[4] = {fq.x, fq.y, fq.z, fq.w};
        const float wa[4] = {wq.x, wq.y, wq.z, wq.w};
        #pragma unroll
        for (int a = 0; a < NAGG; ++a)
          #pragma unroll
          for (int c = 0; c < 4; ++c){
            const float p = wa[a] * fc[c];
            psum[a][c] += p;
            pmax[a][c]  = fmaxf(pmax[a][c], p);
          }
      }
      #pragma unroll
      for (int m = 32; m > 0; m >>= 1){
        #pragma unroll
        for (int a = 0; a < NAGG; ++a)
          #pragma unroll
          for (int c = 0; c < 4; ++c){
            psum[a][c] += __shfl_xor(psum[a][c], m, 64);
            pmax[a][c]  = fmaxf(pmax[a][c], __shfl_xor(pmax[a][c], m, 64));
          }
      }
      if (lane == 0){
        float* gp = wsF + WSF_AGG + (((size_t)(b*2 + (l&1))*2 + half) * NAGG * 48);
        #pragma unroll
        for (int a = 0; a < NAGG; ++a)
          #pragma unroll
          for (int c = 0; c < 4; ++c){
            sAgg[a][g*4 + c]      = pmax[a][c];          // raw partial max
            sAgg[a][24 + g*4 + c] = psum[a][c];          // raw partial sum
            __hip_atomic_store(&gp[a*48 + g*4 + c],      pmax[a][c], __ATOMIC_RELAXED, __HIP_MEMORY_SCOPE_AGENT);
            __hip_atomic_store(&gp[a*48 + 24 + g*4 + c], psum[a][c], __ATOMIC_RELAXED, __HIP_MEMORY_SCOPE_AGENT);
          }
      }
    }
    pair_sync(flag, 2*l + 4);

    // ---- combine halves: max of maxes, mean = (sum0+sum1)/V ----
    if (t < 192){
      const int a = t / 48, c = t - a * 48;
      const float* pp = wsF + WSF_AGG + (((size_t)(b*2 + (l&1))*2 + (half^1)) * NAGG * 48);
      const float mine   = sAgg[a][c];
      const float theirs = __hip_atomic_load(&pp[a*48 + c], __ATOMIC_RELAXED, __HIP_MEMORY_SCOPE_AGENT);
      sAgg[a][c] = (c < 24) ? fmaxf(mine, theirs) : (mine + theirs) * (1.0f / VV);
    }
    __syncthreads();

    // ---- M'[a][j] = sum_c agg[a][c]*Wo[32+a*48+c][j] + Wo[224+a][j] ----
    if (t < 128){
      const int a = t >> 5, j = t & 31;
      float m = Wo[(224 + a) * NFILT + j];
      #pragma unroll 8
      for (int c = 0; c < 48; ++c) m += sAgg[a][c] * Wo[(32 + a*48 + c) * NFILT + j];
      sM[a][j] = m;
    }
    __syncthreads();

    // ---- stage 3: out_j = bn(tanh(h@WoH + w@M' + bo)); acc += out@Wo0_slice ----
    // new h buffered in regs (hn) -- h must stay old for the whole q-loop.
    float hn[NFILT];
    #pragma unroll
    for (int q = 0; q < 8; ++q){
      const float4 m0 = *(const float4*)&sM[0][q*4];
      const float4 m1 = *(const float4*)&sM[1][q*4];
      const float4 m2 = *(const float4*)&sM[2][q*4];
      const float4 m3 = *(const float4*)&sM[3][q*4];
      float val[4];
      #pragma unroll
      for (int jj = 0; jj < 4; ++jj){
        const int j = q*4 + jj;
        const float mqa = (jj==0) ? m0.x : (jj==1) ? m0.y : (jj==2) ? m0.z : m0.w;
        const float mqb = (jj==0) ? m1.x : (jj==1) ? m1.y : (jj==2) ? m1.z : m1.w;
        const float mqc = (jj==0) ? m2.x : (jj==1) ? m2.y : (jj==2) ? m2.z : m2.w;
        const float mqd = (jj==0) ? m3.x : (jj==1) ? m3.y : (jj==2) ? m3.z : m3.w;
        float o = bo[j] + w[0]*mqa + w[1]*mqb + w[2]*mqc + w[3]*mqd;
        #pragma unroll
        for (int k = 0; k < NFILT; ++k) o += h[k] * Wo[k*NFILT + j];
        const float th = fast_tanh(o);
        val[jj] = (th - bm[j]) * (g_[j] * rsqrtf(bv[j] + BN_EPS)) + be[j];
      }
      #pragma unroll
      for (int jj = 0; jj < 4; ++jj){
        const int j = q*4 + jj;
        const float* wrow = W_o0 + ((size_t)(l*NFILT + j)) * 48;
        #pragma unroll
        for (int n = 0; n < 48; ++n) acc[n] += val[jj] * wrow[n];
        hn[j] = val[jj];
      }
    }
    #pragma unroll
    for (int j = 0; j < NFILT; ++j) h[j] = hn[j];
  }

  // ---------------- head: relu(acc48) @ W_o1 + b_o1, relu ----------------
  {
    float o3[3] = {b_o1[0], b_o1[1], b_o1[2]};
    #pragma unroll
    for (int n = 0; n < 48; ++n){
      const float hr = fmaxf(acc[n], 0.f);
      o3[0] += hr * W_o1[n*3 + 0];
      o3[1] += hr * W_o1[n*3 + 1];
      o3[2] += hr * W_o1[n*3 + 2];
    }
    float* op = out + ((size_t)b * VV + v) * 3;
    op[0] = fmaxf(o3[0], 0.f);
    op[1] = fmaxf(o3[1], 0.f);
    op[2] = fmaxf(o3[2], 0.f);
  }
}

extern "C" void kernel_launch(void* const* d_in, const int* in_sizes, int n_in,
                              void* d_out, int out_size, void* d_ws, size_t ws_size,
                              hipStream_t stream) {
  const float* x      = (const float*)d_in[0];
  const float* bn0_g  = (const float*)d_in[1];
  const float* bn0_b  = (const float*)d_in[2];
  const float* bn0_m  = (const float*)d_in[3];
  const float* bn0_v  = (const float*)d_in[4];
  const float* W_in   = (const float*)d_in[5];
  const float* b_in   = (const float*)d_in[6];
  const float* W_flr  = (const float*)d_in[7];
  const float* b_flr  = (const float*)d_in[8];
  const float* W_s    = (const float*)d_in[9];
  const float* b_s    = (const float*)d_in[10];
  const float* W_out  = (const float*)d_in[11];
  const float* b_out  = (const float*)d_in[12];
  const float* bn_g   = (const float*)d_in[13];
  const float* bn_b   = (const float*)d_in[14];
  const float* bn_m   = (const float*)d_in[15];
  const float* bn_v   = (const float*)d_in[16];
  const float* W_o0   = (const float*)d_in[17];
  const float* b_o0   = (const float*)d_in[18];
  const float* W_o1   = (const float*)d_in[19];
  const float* b_o1   = (const float*)d_in[20];

  // reset pairwise sync flags (graph-capture-safe)
  hipMemsetAsync(d_ws, 0, BB * sizeof(int), stream);

  garnet_fused<<<dim3(BB * 2), dim3(TPB), 0, stream>>>(
      x, bn0_g, bn0_b, bn0_m, bn0_v, W_in, b_in,
      W_flr, b_flr, W_s, b_s, W_out, b_out,
      bn_g, bn_b, bn_m, bn_v, W_o0, b_o0, W_o1, b_o1,
      (int*)d_ws, (float*)d_ws, (float*)d_out);
}

// Round 6
// 1308.340 us; speedup vs baseline: 1.5223x; 1.2083x over previous
//
#include <hip/hip_runtime.h>
#include <math.h>

#define NBLK  11
#define NAGG  4
#define NFILT 32
#define NPROP 20
#define BB    128
#define VV    1024
#define FIN   10
#define TPB   1024
#define BN_EPS 1e-3f

__device__ __forceinline__ float fast_tanh(float x){
  float a = fabsf(x);
  float e = __expf(-2.0f * a);
  float r = (1.0f - e) / (1.0f + e);
  return copysignf(r, x);
}

// One 1024-thread WG per event: all V-wide reductions stay inside the WG.
// No cross-WG sync, no agent-scope fences, no workspace.
// 4 waves/SIMD -> hard 128-VGPR cap; live set designed to fit under it:
//   persistent h[32]+acc[48]+w[4]=84; stage2 split 12 ways (16 acc regs);
//   stage3 round-trips new-h through LDS (register-cheap).
extern "C" __global__ __launch_bounds__(TPB)
void garnet_fused(
    const float* __restrict__ x,
    const float* __restrict__ bn0_g, const float* __restrict__ bn0_b,
    const float* __restrict__ bn0_m, const float* __restrict__ bn0_v,
    const float* __restrict__ W_in,  const float* __restrict__ b_in,
    const float* __restrict__ W_flr, const float* __restrict__ b_flr,
    const float* __restrict__ W_s,   const float* __restrict__ b_s,
    const float* __restrict__ W_out, const float* __restrict__ b_out,
    const float* __restrict__ bn_g,  const float* __restrict__ bn_b,
    const float* __restrict__ bn_m,  const float* __restrict__ bn_v,
    const float* __restrict__ W_o0,  const float* __restrict__ b_o0,
    const float* __restrict__ W_o1,  const float* __restrict__ b_o1,
    float* __restrict__ out)
{
  const int b    = blockIdx.x;
  const int t    = threadIdx.x;      // vertex this thread owns
  const int lane = t & 63;
  const int wave = t >> 6;
  const int sw   = t & 7;            // LDS granule swizzle for own row

  __shared__ float sFeat[VV][32];    // 128 KB, rows 128B, XOR-swizzled granules
  __shared__ float sAgg[NAGG][48];
  __shared__ float sM[NAGG][NFILT];
  __shared__ float sRed[16][FIN];
  __shared__ float sMean[FIN];

  // ---------------- phase 0: mean over V + input dense ----------------
  float h[NFILT];
  {
    float xv[FIN];
    const float* xp = x + ((size_t)b * VV + t) * FIN;
    #pragma unroll
    for (int c = 0; c < FIN; ++c) xv[c] = xp[c];

    float ps[FIN];
    #pragma unroll
    for (int c = 0; c < FIN; ++c) ps[c] = xv[c];
    #pragma unroll
    for (int m = 32; m > 0; m >>= 1){
      #pragma unroll
      for (int c = 0; c < FIN; ++c) ps[c] += __shfl_xor(ps[c], m, 64);
    }
    if (lane == 0){
      #pragma unroll
      for (int c = 0; c < FIN; ++c) sRed[wave][c] = ps[c];
    }
    __syncthreads();
    if (t < FIN){
      float s = 0.f;
      #pragma unroll
      for (int wv = 0; wv < 16; ++wv) s += sRed[wv][t];
      sMean[t] = s * (1.0f / VV);
    }
    __syncthreads();

    // h = tanh(bn0(concat(x,mean)) @ W_in + b_in)
    float o[NFILT];
    #pragma unroll
    for (int j = 0; j < NFILT; ++j) o[j] = b_in[j];
    #pragma unroll
    for (int c = 0; c < FIN; ++c){
      const float zx = (xv[c]    - bn0_m[c])     * (bn0_g[c]     * rsqrtf(bn0_v[c]     + BN_EPS)) + bn0_b[c];
      const float zm = (sMean[c] - bn0_m[FIN+c]) * (bn0_g[FIN+c] * rsqrtf(bn0_v[FIN+c] + BN_EPS)) + bn0_b[FIN+c];
      #pragma unroll
      for (int j = 0; j < NFILT; ++j)
        o[j] += zx * W_in[c*NFILT + j] + zm * W_in[(FIN+c)*NFILT + j];
    }
    #pragma unroll
    for (int j = 0; j < NFILT; ++j) h[j] = fast_tanh(o[j]);
  }

  // fused head accumulator: acc48 = b_o0 + sum_l out_l @ W_o0[l*32:(l+1)*32,:]
  float acc[48];
  #pragma unroll
  for (int n = 0; n < 48; ++n) acc[n] = b_o0[n];

  float w[NAGG];

  for (int l = 0; l < NBLK; ++l){
    const float* Wf = W_flr + l * NFILT * NPROP;
    const float* bf = b_flr + l * NPROP;
    const float* Ws = W_s   + l * NFILT * NAGG;
    const float* bs = b_s   + l * NAGG;
    const float* Wo = W_out + l * 228 * NFILT;
    const float* bo = b_out + l * NFILT;
    const float* g_ = bn_g  + l * NFILT;
    const float* be = bn_b  + l * NFILT;
    const float* bm = bn_m  + l * NFILT;
    const float* bv = bn_v  + l * NFILT;

    // ---- stage 1: f = h@Wf+bf, d = h@Ws+bs, w = exp(-|d|); feat -> LDS ----
    {
      float f[NPROP];
      #pragma unroll
      for (int p = 0; p < NPROP; ++p) f[p] = bf[p];
      float d[NAGG];
      #pragma unroll
      for (int a = 0; a < NAGG; ++a) d[a] = bs[a];
      #pragma unroll
      for (int k = 0; k < NFILT; ++k){
        const float hk = h[k];
        #pragma unroll
        for (int p = 0; p < NPROP; ++p) f[p] += hk * Wf[k*NPROP + p];
        #pragma unroll
        for (int a = 0; a < NAGG; ++a)  d[a] += hk * Ws[k*NAGG + a];
      }
      #pragma unroll
      for (int a = 0; a < NAGG; ++a) w[a] = __expf(-fabsf(d[a]));
      #pragma unroll
      for (int q = 0; q < 5; ++q)
        *(float4*)&sFeat[t][((q ^ sw) << 2)] = make_float4(f[4*q], f[4*q+1], f[4*q+2], f[4*q+3]);
      *(float4*)&sFeat[t][((5 ^ sw) << 2)] = make_float4(w[0], w[1], w[2], w[3]);
    }
    __syncthreads();

    // ---- stage 2: max/sum over 1024 rows; wave (g,ap) owns c-quad g, a-pair ap ----
    // 12 active waves; per-wave accumulators only 16 regs (psum[2][4]+pmax[2][4]).
    if (wave < 12){
      const int g  = wave >> 1;       // c-quad 0..5
      const int ap = wave & 1;        // a-pair: a in {2ap, 2ap+1}
      float psum[2][4], pmax[2][4];
      #pragma unroll
      for (int aa = 0; aa < 2; ++aa)
        #pragma unroll
        for (int c = 0; c < 4; ++c){ psum[aa][c] = 0.f; pmax[aa][c] = -INFINITY; }
      for (int i = 0; i < 16; ++i){
        const int row = i * 64 + lane;
        const int rs  = row & 7;
        const float4 fq = *(const float4*)&sFeat[row][((g ^ rs) << 2)];
        const float2 wp = *(const float2*)&sFeat[row][((5 ^ rs) << 2) + ap*2];
        const float fc[4] = {fq.x, fq.y, fq.z, fq.w};
        const float wa[2] = {wp.x, wp.y};
        #pragma unroll
        for (int aa = 0; aa < 2; ++aa)
          #pragma unroll
          for (int c = 0; c < 4; ++c){
            const float p = wa[aa] * fc[c];
            psum[aa][c] += p;
            pmax[aa][c]  = fmaxf(pmax[aa][c], p);
          }
      }
      #pragma unroll
      for (int m = 32; m > 0; m >>= 1){
        #pragma unroll
        for (int aa = 0; aa < 2; ++aa)
          #pragma unroll
          for (int c = 0; c < 4; ++c){
            psum[aa][c] += __shfl_xor(psum[aa][c], m, 64);
            pmax[aa][c]  = fmaxf(pmax[aa][c], __shfl_xor(pmax[aa][c], m, 64));
          }
      }
      if (lane == 0){
        #pragma unroll
        for (int aa = 0; aa < 2; ++aa)
          #pragma unroll
          for (int c = 0; c < 4; ++c){
            sAgg[2*ap + aa][g*4 + c]      = pmax[aa][c];
            sAgg[2*ap + aa][24 + g*4 + c] = psum[aa][c] * (1.0f / VV);
          }
      }
    }
    __syncthreads();

    // ---- M'[a][j] = sum_c agg[a][c]*Wo[32+a*48+c][j] + Wo[224+a][j] ----
    if (t < 128){
      const int a = t >> 5, j = t & 31;
      float m = Wo[(224 + a) * NFILT + j];
      #pragma unroll 8
      for (int c = 0; c < 48; ++c) m += sAgg[a][c] * Wo[(32 + a*48 + c) * NFILT + j];
      sM[a][j] = m;
    }
    __syncthreads();

    // ---- stage 3: out_j = bn(tanh(h@WoH + w@M' + bo)); acc += out@Wo0_slice ----
    // new-h round-trips through own LDS row (register-cheap under the 128 cap).
    #pragma unroll
    for (int q = 0; q < 8; ++q){
      const float4 m0 = *(const float4*)&sM[0][q*4];
      const float4 m1 = *(const float4*)&sM[1][q*4];
      const float4 m2 = *(const float4*)&sM[2][q*4];
      const float4 m3 = *(const float4*)&sM[3][q*4];
      float val[4];
      #pragma unroll
      for (int jj = 0; jj < 4; ++jj){
        const int j = q*4 + jj;
        const float mqa = (jj==0) ? m0.x : (jj==1) ? m0.y : (jj==2) ? m0.z : m0.w;
        const float mqb = (jj==0) ? m1.x : (jj==1) ? m1.y : (jj==2) ? m1.z : m1.w;
        const float mqc = (jj==0) ? m2.x : (jj==1) ? m2.y : (jj==2) ? m2.z : m2.w;
        const float mqd = (jj==0) ? m3.x : (jj==1) ? m3.y : (jj==2) ? m3.z : m3.w;
        float o = bo[j] + w[0]*mqa + w[1]*mqb + w[2]*mqc + w[3]*mqd;
        #pragma unroll
        for (int k = 0; k < NFILT; ++k) o += h[k] * Wo[k*NFILT + j];
        const float th = fast_tanh(o);
        val[jj] = (th - bm[j]) * (g_[j] * rsqrtf(bv[j] + BN_EPS)) + be[j];
      }
      #pragma unroll
      for (int jj = 0; jj < 4; ++jj){
        const int j = q*4 + jj;
        const float* wrow = W_o0 + ((size_t)(l*NFILT + j)) * 48;
        #pragma unroll
        for (int n = 0; n < 48; ++n) acc[n] += val[jj] * wrow[n];
      }
      *(float4*)&sFeat[t][((q ^ sw) << 2)] = make_float4(val[0], val[1], val[2], val[3]);
    }
    // reload new h from own row (no barrier: own row only)
    #pragma unroll
    for (int q = 0; q < 8; ++q){
      const float4 hv = *(const float4*)&sFeat[t][((q ^ sw) << 2)];
      h[4*q+0] = hv.x; h[4*q+1] = hv.y; h[4*q+2] = hv.z; h[4*q+3] = hv.w;
    }
  }

  // ---------------- head: relu(acc48) @ W_o1 + b_o1, relu ----------------
  {
    float o3[3] = {b_o1[0], b_o1[1], b_o1[2]};
    #pragma unroll
    for (int n = 0; n < 48; ++n){
      const float hr = fmaxf(acc[n], 0.f);
      o3[0] += hr * W_o1[n*3 + 0];
      o3[1] += hr * W_o1[n*3 + 1];
      o3[2] += hr * W_o1[n*3 + 2];
    }
    float* op = out + ((size_t)b * VV + t) * 3;
    op[0] = fmaxf(o3[0], 0.f);
    op[1] = fmaxf(o3[1], 0.f);
    op[2] = fmaxf(o3[2], 0.f);
  }
}

extern "C" void kernel_launch(void* const* d_in, const int* in_sizes, int n_in,
                              void* d_out, int out_size, void* d_ws, size_t ws_size,
                              hipStream_t stream) {
  const float* x      = (const float*)d_in[0];
  const float* bn0_g  = (const float*)d_in[1];
  const float* bn0_b  = (const float*)d_in[2];
  const float* bn0_m  = (const float*)d_in[3];
  const float* bn0_v  = (const float*)d_in[4];
  const float* W_in   = (const float*)d_in[5];
  const float* b_in   = (const float*)d_in[6];
  const float* W_flr  = (const float*)d_in[7];
  const float* b_flr  = (const float*)d_in[8];
  const float* W_s    = (const float*)d_in[9];
  const float* b_s    = (const float*)d_in[10];
  const float* W_out  = (const float*)d_in[11];
  const float* b_out  = (const float*)d_in[12];
  const float* bn_g   = (const float*)d_in[13];
  const float* bn_b   = (const float*)d_in[14];
  const float* bn_m   = (const float*)d_in[15];
  const float* bn_v   = (const float*)d_in[16];
  const float* W_o0   = (const float*)d_in[17];
  const float* b_o0   = (const float*)d_in[18];
  const float* W_o1   = (const float*)d_in[19];
  const float* b_o1   = (const float*)d_in[20];

  garnet_fused<<<dim3(BB), dim3(TPB), 0, stream>>>(
      x, bn0_g, bn0_b, bn0_m, bn0_v, W_in, b_in,
      W_flr, b_flr, W_s, b_s, W_out, b_out,
      bn_g, bn_b, bn_m, bn_v, W_o0, b_o0, W_o1, b_o1,
      (float*)d_out);
}

// Round 7
// 308.777 us; speedup vs baseline: 6.4501x; 4.2372x over previous
//
#include <hip/hip_runtime.h>
#include <math.h>

#define NBLK  11
#define NAGG  4
#define NFILT 32
#define NPROP 20
#define BB    128
#define VV    1024
#define HV    512
#define FIN   10
#define TPB   512
#define BN_EPS 1e-3f

// d_ws: [0..127] int flags (memset 0 per launch); floats after.
#define WSF_MEAN 128
#define WSF_AGG  (WSF_MEAN + BB*2*FIN)

__device__ __forceinline__ float fast_tanh(float x){
  float a = fabsf(x);
  float e = __expf(-2.0f * a);
  float r = (1.0f - e) / (1.0f + e);
  return copysignf(r, x);
}

// pairwise event sync: each WG posts once (RELEASE), spins (ACQUIRE).
__device__ __forceinline__ void pair_sync(int* flag, int target){
  __syncthreads();
  if (threadIdx.x == 0){
    __hip_atomic_fetch_add(flag, 1, __ATOMIC_RELEASE, __HIP_MEMORY_SCOPE_AGENT);
    while (__hip_atomic_load(flag, __ATOMIC_ACQUIRE, __HIP_MEMORY_SCOPE_AGENT) < target)
      __builtin_amdgcn_s_sleep(2);
  }
  __syncthreads();
}

// TPB=512 -> observed hard VGPR cap = 65536/TPB = 128 (allocator ignores LDS
// and occupancy attrs). Design: persistent regs only h[32]+w[4]; per-vertex
// acc48 lives in LDS (sAcc, 49-stride = bank-bijective); stage-3 transient
// racc[48] is live only while o[32] is dead. Peak live ~110 < 128 -> no spill.
extern "C" __global__ __launch_bounds__(TPB)
void garnet_fused(
    const float* __restrict__ x,
    const float* __restrict__ bn0_g, const float* __restrict__ bn0_b,
    const float* __restrict__ bn0_m, const float* __restrict__ bn0_v,
    const float* __restrict__ W_in,  const float* __restrict__ b_in,
    const float* __restrict__ W_flr, const float* __restrict__ b_flr,
    const float* __restrict__ W_s,   const float* __restrict__ b_s,
    const float* __restrict__ W_out, const float* __restrict__ b_out,
    const float* __restrict__ bn_g,  const float* __restrict__ bn_b,
    const float* __restrict__ bn_m,  const float* __restrict__ bn_v,
    const float* __restrict__ W_o0,  const float* __restrict__ b_o0,
    const float* __restrict__ W_o1,  const float* __restrict__ b_o1,
    int* __restrict__ wsFlag, float* __restrict__ wsF,
    float* __restrict__ out)
{
  const int wg   = blockIdx.x;
  const int b    = wg & (BB - 1);     // partner = wg^128 (same XCD by %8)
  const int half = wg >> 7;
  const int t    = threadIdx.x;
  const int lane = t & 63;
  const int wave = t >> 6;
  const int v    = half * HV + t;     // global vertex this thread owns

  __shared__ float sFeat[HV * 25];    // 50 KB; row stride 25 (bank-bijective)
  __shared__ float sAcc [HV * 49];    // 98 KB; row stride 49 (bank-bijective)
  __shared__ float sAgg[NAGG][48];
  __shared__ float sM[NAGG][NFILT];
  __shared__ float sRed[8][FIN];
  __shared__ float sMean[FIN];

  int* flag = wsFlag + b;

  // ---------------- phase 0: mean over V (cross-half) + input dense ----------------
  float h[NFILT], w[NAGG];
  {
    float xv[FIN];
    const float* xp = x + ((size_t)b * VV + v) * FIN;
    #pragma unroll
    for (int c = 0; c < FIN; ++c) xv[c] = xp[c];

    float ps[FIN];
    #pragma unroll
    for (int c = 0; c < FIN; ++c) ps[c] = xv[c];
    #pragma unroll
    for (int m = 32; m > 0; m >>= 1){
      #pragma unroll
      for (int c = 0; c < FIN; ++c) ps[c] += __shfl_xor(ps[c], m, 64);
    }
    if (lane == 0){
      #pragma unroll
      for (int c = 0; c < FIN; ++c) sRed[wave][c] = ps[c];
    }
    __syncthreads();
    if (t < FIN){
      float s = 0.f;
      #pragma unroll
      for (int wv = 0; wv < 8; ++wv) s += sRed[wv][t];
      sRed[0][t] = s;
      __hip_atomic_store(&wsF[WSF_MEAN + (b*2 + half)*FIN + t], s,
                         __ATOMIC_RELAXED, __HIP_MEMORY_SCOPE_AGENT);
    }
    pair_sync(flag, 2);
    if (t < FIN){
      float theirs = __hip_atomic_load(&wsF[WSF_MEAN + (b*2 + (half^1))*FIN + t],
                                       __ATOMIC_RELAXED, __HIP_MEMORY_SCOPE_AGENT);
      sMean[t] = (sRed[0][t] + theirs) * (1.0f / VV);
    }
    __syncthreads();

    // h = tanh(bn0(concat(x,mean)) @ W_in + b_in)
    float o[NFILT];
    #pragma unroll
    for (int j = 0; j < NFILT; ++j) o[j] = b_in[j];
    #pragma unroll
    for (int c = 0; c < FIN; ++c){
      const float zx = (xv[c]    - bn0_m[c])     * (bn0_g[c]     * rsqrtf(bn0_v[c]     + BN_EPS)) + bn0_b[c];
      const float zm = (sMean[c] - bn0_m[FIN+c]) * (bn0_g[FIN+c] * rsqrtf(bn0_v[FIN+c] + BN_EPS)) + bn0_b[FIN+c];
      #pragma unroll
      for (int j = 0; j < NFILT; ++j)
        o[j] += zx * W_in[c*NFILT + j] + zm * W_in[(FIN+c)*NFILT + j];
    }
    #pragma unroll
    for (int j = 0; j < NFILT; ++j) h[j] = fast_tanh(o[j]);
  }

  // per-vertex head accumulator lives in LDS (own row only, never cross-thread)
  #pragma unroll
  for (int n = 0; n < 48; ++n) sAcc[t*49 + n] = b_o0[n];

  for (int l = 0; l < NBLK; ++l){
    const float* Wf = W_flr + l * NFILT * NPROP;
    const float* bf = b_flr + l * NPROP;
    const float* Ws = W_s   + l * NFILT * NAGG;
    const float* bs = b_s   + l * NAGG;
    const float* Wo = W_out + l * 228 * NFILT;
    const float* bo = b_out + l * NFILT;
    const float* g_ = bn_g  + l * NFILT;
    const float* be = bn_b  + l * NFILT;
    const float* bm = bn_m  + l * NFILT;
    const float* bv = bn_v  + l * NFILT;

    // ---- stage 1: f = h@Wf+bf, d = h@Ws+bs, w = exp(-|d|); f,w -> sFeat row ----
    {
      float f[NPROP];
      #pragma unroll
      for (int p = 0; p < NPROP; ++p) f[p] = bf[p];
      float d[NAGG];
      #pragma unroll
      for (int a = 0; a < NAGG; ++a) d[a] = bs[a];
      #pragma unroll
      for (int k = 0; k < NFILT; ++k){
        const float hk = h[k];
        #pragma unroll
        for (int p = 0; p < NPROP; ++p) f[p] += hk * Wf[k*NPROP + p];
        #pragma unroll
        for (int a = 0; a < NAGG; ++a)  d[a] += hk * Ws[k*NAGG + a];
      }
      #pragma unroll
      for (int a = 0; a < NAGG; ++a) w[a] = __expf(-fabsf(d[a]));
      #pragma unroll
      for (int p = 0; p < NPROP; ++p) sFeat[t*25 + p] = f[p];
      #pragma unroll
      for (int a = 0; a < NAGG; ++a)  sFeat[t*25 + NPROP + a] = w[a];
    }
    __syncthreads();

    // ---- stage 2: partial max/sum over 512 rows; wave g (g<6) owns c-quad g ----
    if (wave < 6){
      const int g = wave;
      float psum[NAGG][4], pmax[NAGG][4];
      #pragma unroll
      for (int a = 0; a < NAGG; ++a)
        #pragma unroll
        for (int c = 0; c < 4; ++c){ psum[a][c] = 0.f; pmax[a][c] = -INFINITY; }
      for (int i = 0; i < 8; ++i){
        const int row = i * 64 + lane;
        float fc[4], wa[4];
        #pragma unroll
        for (int c = 0; c < 4; ++c) fc[c] = sFeat[row*25 + g*4 + c];
        #pragma unroll
        for (int a = 0; a < 4; ++a) wa[a] = sFeat[row*25 + NPROP + a];
        #pragma unroll
        for (int a = 0; a < NAGG; ++a)
          #pragma unroll
          for (int c = 0; c < 4; ++c){
            const float p = wa[a] * fc[c];
            psum[a][c] += p;
            pmax[a][c]  = fmaxf(pmax[a][c], p);
          }
      }
      #pragma unroll
      for (int m = 32; m > 0; m >>= 1){
        #pragma unroll
        for (int a = 0; a < NAGG; ++a)
          #pragma unroll
          for (int c = 0; c < 4; ++c){
            psum[a][c] += __shfl_xor(psum[a][c], m, 64);
            pmax[a][c]  = fmaxf(pmax[a][c], __shfl_xor(pmax[a][c], m, 64));
          }
      }
      if (lane == 0){
        float* gp = wsF + WSF_AGG + (((size_t)(b*2 + (l&1))*2 + half) * NAGG * 48);
        #pragma unroll
        for (int a = 0; a < NAGG; ++a)
          #pragma unroll
          for (int c = 0; c < 4; ++c){
            sAgg[a][g*4 + c]      = pmax[a][c];
            sAgg[a][24 + g*4 + c] = psum[a][c];
            __hip_atomic_store(&gp[a*48 + g*4 + c],      pmax[a][c], __ATOMIC_RELAXED, __HIP_MEMORY_SCOPE_AGENT);
            __hip_atomic_store(&gp[a*48 + 24 + g*4 + c], psum[a][c], __ATOMIC_RELAXED, __HIP_MEMORY_SCOPE_AGENT);
          }
      }
    }
    pair_sync(flag, 2*l + 4);

    // ---- combine halves: max of maxes, mean = (sum0+sum1)/V ----
    if (t < 192){
      const int a = t / 48, c = t - a * 48;
      const float* pp = wsF + WSF_AGG + (((size_t)(b*2 + (l&1))*2 + (half^1)) * NAGG * 48);
      const float mine   = sAgg[a][c];
      const float theirs = __hip_atomic_load(&pp[a*48 + c], __ATOMIC_RELAXED, __HIP_MEMORY_SCOPE_AGENT);
      sAgg[a][c] = (c < 24) ? fmaxf(mine, theirs) : (mine + theirs) * (1.0f / VV);
    }
    __syncthreads();

    // ---- M'[a][j] = sum_c agg[a][c]*Wo[32+a*48+c][j] + Wo[224+a][j] ----
    if (t < 128){
      const int a = t >> 5, j = t & 31;
      float m = Wo[(224 + a) * NFILT + j];
      #pragma unroll 8
      for (int c = 0; c < 48; ++c) m += sAgg[a][c] * Wo[(32 + a*48 + c) * NFILT + j];
      sM[a][j] = m;
    }
    __syncthreads();

    // ---- stage 3, phase A: o[32] = bo + w@M' + h@WoH (h still old) ----
    float o[NFILT];
    #pragma unroll
    for (int j = 0; j < NFILT; ++j) o[j] = bo[j];
    #pragma unroll
    for (int a = 0; a < NAGG; ++a){
      const float wa = w[a];
      #pragma unroll
      for (int j = 0; j < NFILT; ++j) o[j] += wa * sM[a][j];
    }
    #pragma unroll
    for (int k = 0; k < NFILT; ++k){
      const float hk = h[k];
      #pragma unroll
      for (int j = 0; j < NFILT; ++j) o[j] += hk * Wo[k*NFILT + j];
    }
    // ---- phase B: h <- bn(tanh(o)) in place (o dies) ----
    #pragma unroll
    for (int j = 0; j < NFILT; ++j){
      const float th = fast_tanh(o[j]);
      h[j] = (th - bm[j]) * (g_[j] * rsqrtf(bv[j] + BN_EPS)) + be[j];
    }
    // ---- phase C: racc[48] = h_new @ W_o0_slice; one LDS RMW pass ----
    {
      float racc[48];
      #pragma unroll
      for (int n = 0; n < 48; ++n) racc[n] = 0.f;
      #pragma unroll
      for (int j = 0; j < NFILT; ++j){
        const float hj = h[j];
        const float* wrow = W_o0 + ((size_t)(l*NFILT + j)) * 48;
        #pragma unroll
        for (int n = 0; n < 48; ++n) racc[n] += hj * wrow[n];
      }
      #pragma unroll
      for (int n = 0; n < 48; ++n) sAcc[t*49 + n] += racc[n];
    }
  }

  // ---------------- head: relu(acc48) @ W_o1 + b_o1, relu ----------------
  {
    float o3[3] = {b_o1[0], b_o1[1], b_o1[2]};
    #pragma unroll
    for (int n = 0; n < 48; ++n){
      const float hr = fmaxf(sAcc[t*49 + n], 0.f);
      o3[0] += hr * W_o1[n*3 + 0];
      o3[1] += hr * W_o1[n*3 + 1];
      o3[2] += hr * W_o1[n*3 + 2];
    }
    float* op = out + ((size_t)b * VV + v) * 3;
    op[0] = fmaxf(o3[0], 0.f);
    op[1] = fmaxf(o3[1], 0.f);
    op[2] = fmaxf(o3[2], 0.f);
  }
}

extern "C" void kernel_launch(void* const* d_in, const int* in_sizes, int n_in,
                              void* d_out, int out_size, void* d_ws, size_t ws_size,
                              hipStream_t stream) {
  const float* x      = (const float*)d_in[0];
  const float* bn0_g  = (const float*)d_in[1];
  const float* bn0_b  = (const float*)d_in[2];
  const float* bn0_m  = (const float*)d_in[3];
  const float* bn0_v  = (const float*)d_in[4];
  const float* W_in   = (const float*)d_in[5];
  const float* b_in   = (const float*)d_in[6];
  const float* W_flr  = (const float*)d_in[7];
  const float* b_flr  = (const float*)d_in[8];
  const float* W_s    = (const float*)d_in[9];
  const float* b_s    = (const float*)d_in[10];
  const float* W_out  = (const float*)d_in[11];
  const float* b_out  = (const float*)d_in[12];
  const float* bn_g   = (const float*)d_in[13];
  const float* bn_b   = (const float*)d_in[14];
  const float* bn_m   = (const float*)d_in[15];
  const float* bn_v   = (const float*)d_in[16];
  const float* W_o0   = (const float*)d_in[17];
  const float* b_o0   = (const float*)d_in[18];
  const float* W_o1   = (const float*)d_in[19];
  const float* b_o1   = (const float*)d_in[20];

  // reset pairwise sync flags (graph-capture-safe)
  hipMemsetAsync(d_ws, 0, BB * sizeof(int), stream);

  garnet_fused<<<dim3(BB * 2), dim3(TPB), 0, stream>>>(
      x, bn0_g, bn0_b, bn0_m, bn0_v, W_in, b_in,
      W_flr, b_flr, W_s, b_s, W_out, b_out,
      bn_g, bn_b, bn_m, bn_v, W_o0, b_o0, W_o1, b_o1,
      (int*)d_ws, (float*)d_ws, (float*)d_out);
}

// Round 8
// 244.421 us; speedup vs baseline: 8.1484x; 1.2633x over previous
//
#include <hip/hip_runtime.h>
#include <math.h>

#define NBLK  11
#define NAGG  4
#define NFILT 32
#define NPROP 20
#define BB    128
#define VV    1024
#define HV    512
#define FIN   10
#define TPB   512
#define BN_EPS 1e-3f
#define SHS   40   // sH row stride in halves: 80 B = 16B-aligned, 20-bank (2-way max)

#define WSF_MEAN 128
#define WSF_AGG  (WSF_MEAN + BB*2*FIN)

typedef _Float16 f16;
typedef f16   f16x8 __attribute__((ext_vector_type(8)));
typedef float f32x4 __attribute__((ext_vector_type(4)));

__device__ __forceinline__ f32x4 MFMA(f16x8 a, f16x8 b, f32x4 c){
  return __builtin_amdgcn_mfma_f32_16x16x32_f16(a, b, c, 0, 0, 0);
}

__device__ __forceinline__ float fast_tanh(float x){
  float a = fabsf(x);
  float e = __expf(-2.0f * a);
  float r = (1.0f - e) / (1.0f + e);
  return copysignf(r, x);
}

__device__ __forceinline__ void pair_sync(int* flag, int target){
  __syncthreads();
  if (threadIdx.x == 0){
    __hip_atomic_fetch_add(flag, 1, __ATOMIC_RELEASE, __HIP_MEMORY_SCOPE_AGENT);
    while (__hip_atomic_load(flag, __ATOMIC_ACQUIRE, __HIP_MEMORY_SCOPE_AGENT) < target)
      __builtin_amdgcn_s_sleep(2);
  }
  __syncthreads();
}

// MFMA 16x16x32 fragment conventions (gfx950, m89-verified C/D mapping):
//   A: lane holds A[row = lane&15][k = 8*(lane>>4) + j], j=0..7
//   B: lane holds B[k = 8*(lane>>4) + j][col = lane&15]
//   C/D: lane holds C[row = 4*(lane>>4) + q][col = lane&15], q=0..3
// h carried as fp16 hi+lo residual pair -> matmul error ~1e-4/layer.
extern "C" __global__ __launch_bounds__(TPB)
void garnet_fused(
    const float* __restrict__ x,
    const float* __restrict__ bn0_g, const float* __restrict__ bn0_b,
    const float* __restrict__ bn0_m, const float* __restrict__ bn0_v,
    const float* __restrict__ W_in,  const float* __restrict__ b_in,
    const float* __restrict__ W_flr, const float* __restrict__ b_flr,
    const float* __restrict__ W_s,   const float* __restrict__ b_s,
    const float* __restrict__ W_out, const float* __restrict__ b_out,
    const float* __restrict__ bn_g,  const float* __restrict__ bn_b,
    const float* __restrict__ bn_m,  const float* __restrict__ bn_v,
    const float* __restrict__ W_o0,  const float* __restrict__ b_o0,
    const float* __restrict__ W_o1,  const float* __restrict__ b_o1,
    int* __restrict__ wsFlag, float* __restrict__ wsF,
    float* __restrict__ out)
{
  const int wg   = blockIdx.x;
  const int b    = wg & (BB - 1);
  const int half = wg >> 7;
  const int t    = threadIdx.x;
  const int lane = t & 63;
  const int wave = t >> 6;
  const int v    = half * HV + t;
  const int l16  = lane & 15;
  const int kb   = lane >> 4;

  __shared__ float sFeat[HV * 25];                 // 50 KB fp32 (stage2 proven)
  __shared__ __align__(16) f16 sHhi[HV * SHS];     // 40 KB
  __shared__ __align__(16) f16 sHlo[HV * SHS];     // 40 KB
  __shared__ f16   sMh[4 * 32];                    // M' fp16 for B-frags
  __shared__ float sAgg[NAGG][48];
  __shared__ float sRed[8][FIN];
  __shared__ float sMean[FIN];

  int* flag = wsFlag + b;

  // ---------------- phase 0: mean over V (cross-half) + input dense ----------------
  {
    float h[NFILT];
    float xv[FIN];
    const float* xp = x + ((size_t)b * VV + v) * FIN;
    #pragma unroll
    for (int c = 0; c < FIN; ++c) xv[c] = xp[c];

    float ps[FIN];
    #pragma unroll
    for (int c = 0; c < FIN; ++c) ps[c] = xv[c];
    #pragma unroll
    for (int m = 32; m > 0; m >>= 1){
      #pragma unroll
      for (int c = 0; c < FIN; ++c) ps[c] += __shfl_xor(ps[c], m, 64);
    }
    if (lane == 0){
      #pragma unroll
      for (int c = 0; c < FIN; ++c) sRed[wave][c] = ps[c];
    }
    __syncthreads();
    if (t < FIN){
      float s = 0.f;
      #pragma unroll
      for (int wv = 0; wv < 8; ++wv) s += sRed[wv][t];
      sRed[0][t] = s;
      __hip_atomic_store(&wsF[WSF_MEAN + (b*2 + half)*FIN + t], s,
                         __ATOMIC_RELAXED, __HIP_MEMORY_SCOPE_AGENT);
    }
    pair_sync(flag, 2);
    if (t < FIN){
      float theirs = __hip_atomic_load(&wsF[WSF_MEAN + (b*2 + (half^1))*FIN + t],
                                       __ATOMIC_RELAXED, __HIP_MEMORY_SCOPE_AGENT);
      sMean[t] = (sRed[0][t] + theirs) * (1.0f / VV);
    }
    __syncthreads();

    float o[NFILT];
    #pragma unroll
    for (int j = 0; j < NFILT; ++j) o[j] = b_in[j];
    #pragma unroll
    for (int c = 0; c < FIN; ++c){
      const float zx = (xv[c]    - bn0_m[c])     * (bn0_g[c]     * rsqrtf(bn0_v[c]     + BN_EPS)) + bn0_b[c];
      const float zm = (sMean[c] - bn0_m[FIN+c]) * (bn0_g[FIN+c] * rsqrtf(bn0_v[FIN+c] + BN_EPS)) + bn0_b[FIN+c];
      #pragma unroll
      for (int j = 0; j < NFILT; ++j)
        o[j] += zx * W_in[c*NFILT + j] + zm * W_in[(FIN+c)*NFILT + j];
    }
    #pragma unroll
    for (int j = 0; j < NFILT; ++j) h[j] = fast_tanh(o[j]);

    // dual fp16 write of h into MFMA-A-friendly layout (own row t)
    #pragma unroll
    for (int c = 0; c < 4; ++c){
      f16x8 hh, hl;
      #pragma unroll
      for (int j = 0; j < 8; ++j){
        const float hv = h[c*8 + j];
        const f16 a = (f16)hv;
        hh[j] = a;
        hl[j] = (f16)(hv - (float)a);
      }
      *(f16x8*)&sHhi[t*SHS + c*8] = hh;
      *(f16x8*)&sHlo[t*SHS + c*8] = hl;
    }
  }
  __syncthreads();

  // head accumulator as MFMA C-frags: acc[tile][colblk], col = s*16+l16
  f32x4 acc[4][3];
  #pragma unroll
  for (int s = 0; s < 3; ++s){
    const float a0 = b_o0[s*16 + l16];
    #pragma unroll
    for (int i = 0; i < 4; ++i) acc[i][s] = (f32x4){a0, a0, a0, a0};
  }

  for (int l = 0; l < NBLK; ++l){
    const float* Wf = W_flr + l * NFILT * NPROP;
    const float* bf = b_flr + l * NPROP;
    const float* Ws = W_s   + l * NFILT * NAGG;
    const float* bs = b_s   + l * NAGG;
    const float* Wo = W_out + l * 228 * NFILT;
    const float* bo = b_out + l * NFILT;
    const float* g_ = bn_g  + l * NFILT;
    const float* be = bn_b  + l * NFILT;
    const float* bm = bn_m  + l * NFILT;
    const float* bv = bn_v  + l * NFILT;

    // ---- stage 1 (MFMA): feat = h @ [Wf|Ws], w = exp(-|d|) -> sFeat fp32 ----
    {
      // B1 frags (s=0: cols 0-15 = f; s=1: cols 16-19 f, 20-23 d, 24-31 pad0)
      f16x8 b1f[2];
      #pragma unroll
      for (int s = 0; s < 2; ++s){
        #pragma unroll
        for (int j = 0; j < 8; ++j){
          const int k = kb*8 + j, n = s*16 + l16;
          float val;
          if (s == 0) val = Wf[k*NPROP + n];
          else        val = (n < 20) ? Wf[k*NPROP + n] : (n < 24 ? Ws[k*NAGG + (n-20)] : 0.f);
          b1f[s][j] = (f16)val;
        }
      }
      const float bias0 = bf[l16];
      const int  c1 = 16 + l16;
      const float bias1 = (c1 < 20) ? bf[c1] : (c1 < 24 ? bs[c1-20] : 0.f);

      #pragma unroll
      for (int i = 0; i < 4; ++i){
        const int tb = wave*64 + i*16;
        const f16x8 ahi = *(const f16x8*)&sHhi[(tb + l16)*SHS + kb*8];
        const f16x8 alo = *(const f16x8*)&sHlo[(tb + l16)*SHS + kb*8];
        f32x4 c0 = (f32x4){bias0, bias0, bias0, bias0};
        c0 = MFMA(ahi, b1f[0], c0);
        c0 = MFMA(alo, b1f[0], c0);
        #pragma unroll
        for (int q = 0; q < 4; ++q)
          sFeat[(tb + kb*4 + q)*25 + l16] = c0[q];
        f32x4 c1v = (f32x4){bias1, bias1, bias1, bias1};
        c1v = MFMA(ahi, b1f[1], c1v);
        c1v = MFMA(alo, b1f[1], c1v);
        if (l16 < 4){
          #pragma unroll
          for (int q = 0; q < 4; ++q)
            sFeat[(tb + kb*4 + q)*25 + 16 + l16] = c1v[q];
        } else if (l16 < 8){
          #pragma unroll
          for (int q = 0; q < 4; ++q)
            sFeat[(tb + kb*4 + q)*25 + 16 + l16] = __expf(-fabsf(c1v[q]));
        }
      }
    }
    __syncthreads();

    // ---- stage 2: partial max/sum over 512 rows; wave g (g<6) owns c-quad g ----
    if (wave < 6){
      const int g = wave;
      float psum[NAGG][4], pmax[NAGG][4];
      #pragma unroll
      for (int a = 0; a < NAGG; ++a)
        #pragma unroll
        for (int c = 0; c < 4; ++c){ psum[a][c] = 0.f; pmax[a][c] = -INFINITY; }
      for (int i = 0; i < 8; ++i){
        const int row = i * 64 + lane;
        float fc[4], wa[4];
        #pragma unroll
        for (int c = 0; c < 4; ++c) fc[c] = sFeat[row*25 + g*4 + c];
        #pragma unroll
        for (int a = 0; a < 4; ++a) wa[a] = sFeat[row*25 + NPROP + a];
        #pragma unroll
        for (int a = 0; a < NAGG; ++a)
          #pragma unroll
          for (int c = 0; c < 4; ++c){
            const float p = wa[a] * fc[c];
            psum[a][c] += p;
            pmax[a][c]  = fmaxf(pmax[a][c], p);
          }
      }
      #pragma unroll
      for (int m = 32; m > 0; m >>= 1){
        #pragma unroll
        for (int a = 0; a < NAGG; ++a)
          #pragma unroll
          for (int c = 0; c < 4; ++c){
            psum[a][c] += __shfl_xor(psum[a][c], m, 64);
            pmax[a][c]  = fmaxf(pmax[a][c], __shfl_xor(pmax[a][c], m, 64));
          }
      }
      if (lane == 0){
        float* gp = wsF + WSF_AGG + (((size_t)(b*2 + (l&1))*2 + half) * NAGG * 48);
        #pragma unroll
        for (int a = 0; a < NAGG; ++a)
          #pragma unroll
          for (int c = 0; c < 4; ++c){
            sAgg[a][g*4 + c]      = pmax[a][c];
            sAgg[a][24 + g*4 + c] = psum[a][c];
            __hip_atomic_store(&gp[a*48 + g*4 + c],      pmax[a][c], __ATOMIC_RELAXED, __HIP_MEMORY_SCOPE_AGENT);
            __hip_atomic_store(&gp[a*48 + 24 + g*4 + c], psum[a][c], __ATOMIC_RELAXED, __HIP_MEMORY_SCOPE_AGENT);
          }
      }
    }
    pair_sync(flag, 2*l + 4);

    if (t < 192){
      const int a = t / 48, c = t - a * 48;
      const float* pp = wsF + WSF_AGG + (((size_t)(b*2 + (l&1))*2 + (half^1)) * NAGG * 48);
      const float mine   = sAgg[a][c];
      const float theirs = __hip_atomic_load(&pp[a*48 + c], __ATOMIC_RELAXED, __HIP_MEMORY_SCOPE_AGENT);
      sAgg[a][c] = (c < 24) ? fmaxf(mine, theirs) : (mine + theirs) * (1.0f / VV);
    }
    __syncthreads();

    // ---- M'[a][j] -> fp16 (B-frag source for w@M') ----
    if (t < 128){
      const int a = t >> 5, j = t & 31;
      float m = Wo[(224 + a) * NFILT + j];
      #pragma unroll 8
      for (int c = 0; c < 48; ++c) m += sAgg[a][c] * Wo[(32 + a*48 + c) * NFILT + j];
      sMh[a*32 + j] = (f16)m;
    }
    __syncthreads();

    // ---- stage 3 (MFMA): o = h@WoH + w@M' + bo; h_new = bn(tanh(o)) -> sH ----
    {
      f16x8 b2f[2], bmf[2];
      #pragma unroll
      for (int s = 0; s < 2; ++s){
        #pragma unroll
        for (int j = 0; j < 8; ++j){
          const int k = kb*8 + j;
          b2f[s][j] = (f16)Wo[k*NFILT + s*16 + l16];
          bmf[s][j] = (kb == 0 && j < 4) ? sMh[j*32 + s*16 + l16] : (f16)0.f;
        }
      }
      // per-lane epilogue constants (col = s*16 + l16)
      float boc[2], bmc[2], scc[2], bec[2];
      #pragma unroll
      for (int s = 0; s < 2; ++s){
        const int cc = s*16 + l16;
        boc[s] = bo[cc];
        bmc[s] = bm[cc];
        scc[s] = g_[cc] * rsqrtf(bv[cc] + BN_EPS);
        bec[s] = be[cc];
      }

      #pragma unroll
      for (int i = 0; i < 4; ++i){
        const int tb = wave*64 + i*16;
        const f16x8 ahi = *(const f16x8*)&sHhi[(tb + l16)*SHS + kb*8];
        const f16x8 alo = *(const f16x8*)&sHlo[(tb + l16)*SHS + kb*8];
        // wA frag: row = vertex, k = aggregator index (only kb==0, j<4 nonzero)
        f16x8 wa;
        #pragma unroll
        for (int j = 0; j < 8; ++j) wa[j] = (f16)0.f;
        {
          const float w0 = sFeat[(tb + l16)*25 + 20];
          const float w1 = sFeat[(tb + l16)*25 + 21];
          const float w2 = sFeat[(tb + l16)*25 + 22];
          const float w3 = sFeat[(tb + l16)*25 + 23];
          if (kb == 0){ wa[0]=(f16)w0; wa[1]=(f16)w1; wa[2]=(f16)w2; wa[3]=(f16)w3; }
        }
        #pragma unroll
        for (int s = 0; s < 2; ++s){
          f32x4 o = (f32x4){0.f, 0.f, 0.f, 0.f};
          o = MFMA(ahi, b2f[s], o);
          o = MFMA(alo, b2f[s], o);
          o = MFMA(wa,  bmf[s], o);
          #pragma unroll
          for (int q = 0; q < 4; ++q){
            const float th = fast_tanh(o[q] + boc[s]);
            const float hn = (th - bmc[s]) * scc[s] + bec[s];
            const f16 hh = (f16)hn;
            const int idx = (tb + kb*4 + q)*SHS + s*16 + l16;
            sHhi[idx] = hh;
            sHlo[idx] = (f16)(hn - (float)hh);
          }
        }
      }
    }
    asm volatile("s_waitcnt lgkmcnt(0)" ::: "memory");

    // ---- phase C (MFMA): acc += h_new @ W_o0_slice ----
    {
      const float* Wo0l = W_o0 + (size_t)l * NFILT * 48;
      f16x8 b3f[3];
      #pragma unroll
      for (int s = 0; s < 3; ++s)
        #pragma unroll
        for (int j = 0; j < 8; ++j)
          b3f[s][j] = (f16)Wo0l[(kb*8 + j)*48 + s*16 + l16];
      #pragma unroll
      for (int i = 0; i < 4; ++i){
        const int tb = wave*64 + i*16;
        const f16x8 ahi = *(const f16x8*)&sHhi[(tb + l16)*SHS + kb*8];
        const f16x8 alo = *(const f16x8*)&sHlo[(tb + l16)*SHS + kb*8];
        #pragma unroll
        for (int s = 0; s < 3; ++s){
          acc[i][s] = MFMA(ahi, b3f[s], acc[i][s]);
          acc[i][s] = MFMA(alo, b3f[s], acc[i][s]);
        }
      }
    }
  }

  // ---------------- head: out = relu(relu(acc) @ W_o1 + b_o1), from C-frags ----------------
  {
    float w1c[3][3];
    #pragma unroll
    for (int s = 0; s < 3; ++s)
      #pragma unroll
      for (int m = 0; m < 3; ++m) w1c[s][m] = W_o1[(s*16 + l16)*3 + m];
    const float bo1_0 = b_o1[0], bo1_1 = b_o1[1], bo1_2 = b_o1[2];

    #pragma unroll
    for (int i = 0; i < 4; ++i){
      const int tb = wave*64 + i*16;
      float p[4][3];
      #pragma unroll
      for (int q = 0; q < 4; ++q){ p[q][0]=0.f; p[q][1]=0.f; p[q][2]=0.f; }
      #pragma unroll
      for (int s = 0; s < 3; ++s)
        #pragma unroll
        for (int q = 0; q < 4; ++q){
          const float r_ = fmaxf(acc[i][s][q], 0.f);
          p[q][0] += r_ * w1c[s][0];
          p[q][1] += r_ * w1c[s][1];
          p[q][2] += r_ * w1c[s][2];
        }
      #pragma unroll
      for (int m = 1; m <= 8; m <<= 1)
        #pragma unroll
        for (int q = 0; q < 4; ++q){
          p[q][0] += __shfl_xor(p[q][0], m, 64);
          p[q][1] += __shfl_xor(p[q][1], m, 64);
          p[q][2] += __shfl_xor(p[q][2], m, 64);
        }
      if (l16 < 3){
        const float bo1v = (l16 == 0) ? bo1_0 : ((l16 == 1) ? bo1_1 : bo1_2);
        #pragma unroll
        for (int q = 0; q < 4; ++q){
          const float vv = (l16 == 0) ? p[q][0] : ((l16 == 1) ? p[q][1] : p[q][2]);
          out[((size_t)b*VV + half*HV + tb + kb*4 + q)*3 + l16] = fmaxf(vv + bo1v, 0.f);
        }
      }
    }
  }
}

extern "C" void kernel_launch(void* const* d_in, const int* in_sizes, int n_in,
                              void* d_out, int out_size, void* d_ws, size_t ws_size,
                              hipStream_t stream) {
  const float* x      = (const float*)d_in[0];
  const float* bn0_g  = (const float*)d_in[1];
  const float* bn0_b  = (const float*)d_in[2];
  const float* bn0_m  = (const float*)d_in[3];
  const float* bn0_v  = (const float*)d_in[4];
  const float* W_in   = (const float*)d_in[5];
  const float* b_in   = (const float*)d_in[6];
  const float* W_flr  = (const float*)d_in[7];
  const float* b_flr  = (const float*)d_in[8];
  const float* W_s    = (const float*)d_in[9];
  const float* b_s    = (const float*)d_in[10];
  const float* W_out  = (const float*)d_in[11];
  const float* b_out  = (const float*)d_in[12];
  const float* bn_g   = (const float*)d_in[13];
  const float* bn_b   = (const float*)d_in[14];
  const float* bn_m   = (const float*)d_in[15];
  const float* bn_v   = (const float*)d_in[16];
  const float* W_o0   = (const float*)d_in[17];
  const float* b_o0   = (const float*)d_in[18];
  const float* W_o1   = (const float*)d_in[19];
  const float* b_o1   = (const float*)d_in[20];

  hipMemsetAsync(d_ws, 0, BB * sizeof(int), stream);

  garnet_fused<<<dim3(BB * 2), dim3(TPB), 0, stream>>>(
      x, bn0_g, bn0_b, bn0_m, bn0_v, W_in, b_in,
      W_flr, b_flr, W_s, b_s, W_out, b_out,
      bn_g, bn_b, bn_m, bn_v, W_o0, b_o0, W_o1, b_o1,
      (int*)d_ws, (float*)d_ws, (float*)d_out);
}